// Round 16
// baseline (124.407 us; speedup 1.0000x reference)
//
#include <hip/hip_runtime.h>
#include <math.h>

#define BATCH 2
#define DCH 64
#define PIX (512 * 512)
#define NCLS 5
#define IGNORE_LB 255
#define KSTR 129                      // fixed injective key stride (> MAX_INDEX)
#define NSEG 645                      // KSTR*4 + 128 + 1
#define NBLK 64                       // key/scatter blocks per batch (4096 px each)
#define TI 16                         // pair-tile edge

// ---- workspace layout (bytes) ----
// zero region (zeroed inside k_keys each call):
#define OFF_PAIR  0                                    // float pairsum[BATCH][25]
#define OFF_SUM   256                                  // float sums[BATCH][NSEG][DCH]
#define ZERO_BYTES 330496
// non-zeroed (fully rewritten each call):
#define OFF_CNT   330496                               // uint counts[BATCH][NSEG]
#define OFF_BHIST 341248                               // uint blockHist[BATCH][NBLK][NSEG]
#define OFF_KEYS  671488                               // ushort keys[BATCH][PIX]
#define OFF_POS   2768640                              // uint posOf[BATCH][PIX]
#define OFF_FEATS 4865792                              // ushort(bf16) featS[BATCH][PIX][DCH]

__device__ __forceinline__ unsigned short f2bf(float f) {   // round-to-nearest-even
    unsigned int u = __float_as_uint(f);
    u += 0x7FFFu + ((u >> 16) & 1u);
    return (unsigned short)(u >> 16);
}

// contiguous 4096-px chunk per block; per-block histogram dumped non-atomically.
// Also cooperatively zeroes the pairsum+sums region (first reader: k_segsum).
__global__ void k_keys(const int* __restrict__ lab, const int* __restrict__ idx,
                       unsigned short* __restrict__ keys,
                       unsigned int* __restrict__ blockHist,
                       float4* __restrict__ zeroReg) {
    __shared__ unsigned int hist[NSEG];
    const int b = blockIdx.y, blk = blockIdx.x;
    {   // zero-fold: 128 blocks cover ZERO_BYTES/16 float4s
        const int n4 = ZERO_BYTES / 16;
        const int bid = b * NBLK + blk;
        const int per = (n4 + NBLK * BATCH - 1) / (NBLK * BATCH);
        const int lo = bid * per;
        const int hi = (lo + per < n4) ? lo + per : n4;
        for (int i = lo + threadIdx.x; i < hi; i += blockDim.x)
            zeroReg[i] = make_float4(0.f, 0.f, 0.f, 0.f);
    }
    for (int i = threadIdx.x; i < NSEG; i += blockDim.x) hist[i] = 0u;
    __syncthreads();
    const int4* lb = (const int4*)(lab + (size_t)b * PIX);
    const int4* ib = (const int4*)(idx + (size_t)b * PIX);
    unsigned short* kb = keys + (size_t)b * PIX;
    #pragma unroll
    for (int it = 0; it < 4; ++it) {
        const int g = blk * 1024 + it * 256 + threadIdx.x;   // int4 group
        const int4 l4 = lb[g];
        const int4 x4 = ib[g];
        int k[4];
        k[0] = (l4.x == IGNORE_LB) ? 0 : KSTR * l4.x + x4.x;
        k[1] = (l4.y == IGNORE_LB) ? 0 : KSTR * l4.y + x4.y;
        k[2] = (l4.z == IGNORE_LB) ? 0 : KSTR * l4.z + x4.z;
        k[3] = (l4.w == IGNORE_LB) ? 0 : KSTR * l4.w + x4.w;
        ushort4 o;
        o.x = (unsigned short)k[0]; o.y = (unsigned short)k[1];
        o.z = (unsigned short)k[2]; o.w = (unsigned short)k[3];
        *(ushort4*)(kb + 4 * g) = o;
        #pragma unroll
        for (int j = 0; j < 4; ++j) atomicAdd(&hist[k[j]], 1u);
    }
    __syncthreads();
    unsigned int* bh = blockHist + ((size_t)b * NBLK + blk) * NSEG;
    for (int i = threadIdx.x; i < NSEG; i += blockDim.x) bh[i] = hist[i];
}

// parallel column scan: one 64-lane wave per segment-column; lane = blk.
// Converts blockHist[*][s] to per-block exclusive prefixes; writes counts[s].
__global__ void k_scanA(unsigned int* __restrict__ blockHist,
                        unsigned int* __restrict__ counts) {
    const int b = blockIdx.y;
    const int s = blockIdx.x * 4 + (threadIdx.x >> 6);
    const int lane = threadIdx.x & 63;
    if (s >= NSEG) return;
    unsigned int* col = blockHist + (size_t)b * NBLK * NSEG + s;
    const unsigned int v0 = col[(size_t)lane * NSEG];
    unsigned int v = v0;
    #pragma unroll
    for (int o = 1; o < 64; o <<= 1) {
        unsigned int t = __shfl_up(v, o, 64);
        if (lane >= o) v += t;
    }
    col[(size_t)lane * NSEG] = v - v0;          // exclusive
    if (lane == 63) counts[b * NSEG + s] = v;   // column total
}

// positions via LDS cursor; base recomputed per-block from counts by wave 0.
__global__ void k_scatter(const unsigned short* __restrict__ keys,
                          const unsigned int* __restrict__ blockHist,
                          const unsigned int* __restrict__ counts,
                          unsigned int* __restrict__ posOf) {
    __shared__ unsigned int baseL[NSEG];
    __shared__ unsigned int cur[NSEG];
    const int b = blockIdx.y, blk = blockIdx.x;
    if (threadIdx.x < 64) {
        const int lane = threadIdx.x;
        unsigned int carry = 0u;
        for (int c = 0; c < (NSEG + 63) / 64; ++c) {
            const int s = c * 64 + lane;
            unsigned int v0 = (s < NSEG) ? counts[b * NSEG + s] : 0u;
            unsigned int v = v0;
            #pragma unroll
            for (int o = 1; o < 64; o <<= 1) {
                unsigned int t = __shfl_up(v, o, 64);
                if (lane >= o) v += t;
            }
            if (s < NSEG) baseL[s] = carry + (v - v0);
            carry += __shfl(v, 63, 64);
        }
    }
    __syncthreads();
    const unsigned int* bh = blockHist + ((size_t)b * NBLK + blk) * NSEG;
    for (int s = threadIdx.x; s < NSEG; s += blockDim.x)
        cur[s] = baseL[s] + bh[s];
    __syncthreads();
    const unsigned short* kb = keys + (size_t)b * PIX;
    unsigned int* po = posOf + (size_t)b * PIX;
    #pragma unroll
    for (int it = 0; it < 4; ++it) {
        const int g = blk * 1024 + it * 256 + threadIdx.x;
        const ushort4 k4 = *(const ushort4*)(kb + 4 * g);
        const unsigned short kk[4] = {k4.x, k4.y, k4.z, k4.w};
        #pragma unroll
        for (int j = 0; j < 4; ++j) {
            const unsigned int pos = atomicAdd(&cur[kk[j]], 1u);
            po[4 * g + j] = pos;
        }
    }
}

// transpose [D][P] -> sorted [pos][D] with f32->bf16, 64x64 tiles via LDS
__global__ __launch_bounds__(256) void k_tpose(const float* __restrict__ feat,
                                               const unsigned int* __restrict__ posOf,
                                               unsigned short* __restrict__ featS) {
    __shared__ unsigned short tile[64][72];   // 144B rows (16B-aligned), 9.2KB
    __shared__ unsigned int posLDS[64];
    const int b = blockIdx.y;
    const int P0 = blockIdx.x * 64;
    const int tid = threadIdx.x;
    if (tid < 64) posLDS[tid] = posOf[(size_t)b * PIX + P0 + tid];
    const float* fb = feat + (size_t)b * DCH * PIX;
    #pragma unroll
    for (int i = 0; i < 4; ++i) {
        const int idx = i * 256 + tid;
        const int ch = idx >> 4, px4 = idx & 15;
        const float4 v = *(const float4*)(fb + (size_t)ch * PIX + P0 + 4 * px4);
        const int col = ch ^ ((px4 & 7) << 3);
        tile[4 * px4 + 0][col] = f2bf(v.x);
        tile[4 * px4 + 1][col] = f2bf(v.y);
        tile[4 * px4 + 2][col] = f2bf(v.z);
        tile[4 * px4 + 3][col] = f2bf(v.w);
    }
    __syncthreads();
    unsigned short* fS = featS + (size_t)b * PIX * DCH;
    #pragma unroll
    for (int i = 0; i < 4; ++i) {
        const int idx = i * 256 + tid;
        const int px = idx >> 4, c4 = idx & 15;
        const int col0 = (4 * c4) ^ (((px >> 2) & 7) << 3);
        const uint2 w = *(const uint2*)&tile[px][col0];
        *(uint2*)(fS + ((size_t)posLDS[px]) * DCH + 4 * c4) = w;
    }
}

// sorted segment sums, 512B/wave loads: lane = (r = row-in-quad, c = channel
// quad). Iteration t (unrolled, literal) reads keys of rows 4t..4t+3 via
// v_readlane (literal lane operands — no ds_bpermute) and selects by r.
// Per-row key from binary search over base[] (correct across empty segments).
__global__ __launch_bounds__(256) void k_segsum(const unsigned short* __restrict__ featS,
                                                const unsigned int* __restrict__ counts,
                                                float* __restrict__ sums) {
    __shared__ unsigned int baseL[NSEG];
    const int b = blockIdx.y;
    if (threadIdx.x < 64) {
        const int lane = threadIdx.x;
        unsigned int carry = 0u;
        for (int c = 0; c < (NSEG + 63) / 64; ++c) {
            const int s = c * 64 + lane;
            unsigned int v0 = (s < NSEG) ? counts[b * NSEG + s] : 0u;
            unsigned int v = v0;
            #pragma unroll
            for (int o = 1; o < 64; o <<= 1) {
                unsigned int t = __shfl_up(v, o, 64);
                if (lane >= o) v += t;
            }
            if (s < NSEG) baseL[s] = carry + (v - v0);
            carry += __shfl(v, 63, 64);
        }
    }
    __syncthreads();
    const int lane = threadIdx.x & 63, wid = threadIdx.x >> 6;
    const int q0 = (blockIdx.x * 4 + wid) * 64;
    const unsigned int q = (unsigned int)(q0 + lane);
    int lo = 0, hi = NSEG - 1;
    #pragma unroll
    for (int it = 0; it < 10; ++it) {      // ceil(log2(645)) = 10
        const int mid = (lo + hi + 1) >> 1;
        if (baseL[mid] <= q) lo = mid; else hi = mid - 1;
    }
    const int sk = lo;                     // key of row (q0+lane)
    const int r = lane >> 4, c = lane & 15;
    const unsigned short* fS = featS + (size_t)b * PIX * DCH;
    {
        const int k0 = __shfl(sk, 0, 64), k1 = __shfl(sk, 1, 64);
        const int k2 = __shfl(sk, 2, 64), k3 = __shfl(sk, 3, 64);
        int cur = (r == 0) ? k0 : (r == 1) ? k1 : (r == 2) ? k2 : k3;
        float a0 = 0.f, a1 = 0.f, a2 = 0.f, a3 = 0.f;
        #pragma unroll
        for (int t = 0; t < 16; ++t) {
            const int ka = __shfl(sk, 4 * t + 0, 64);
            const int kb = __shfl(sk, 4 * t + 1, 64);
            const int kc = __shfl(sk, 4 * t + 2, 64);
            const int kd = __shfl(sk, 4 * t + 3, 64);
            const int k = (r == 0) ? ka : (r == 1) ? kb : (r == 2) ? kc : kd;
            const uint2 u = *(const uint2*)(fS + (size_t)(q0 + 4 * t + r) * DCH + 4 * c);
            if (k != cur) {
                float* dst = &sums[((size_t)b * NSEG + cur) * DCH + 4 * c];
                unsafeAtomicAdd(dst + 0, a0);
                unsafeAtomicAdd(dst + 1, a1);
                unsafeAtomicAdd(dst + 2, a2);
                unsafeAtomicAdd(dst + 3, a3);
                a0 = a1 = a2 = a3 = 0.f;
                cur = k;
            }
            a0 += __uint_as_float(u.x << 16);
            a1 += __uint_as_float(u.x & 0xffff0000u);
            a2 += __uint_as_float(u.y << 16);
            a3 += __uint_as_float(u.y & 0xffff0000u);
        }
        float* dst = &sums[((size_t)b * NSEG + cur) * DCH + 4 * c];
        unsafeAtomicAdd(dst + 0, a0);
        unsafeAtomicAdd(dst + 1, a1);
        unsafeAtomicAdd(dst + 2, a2);
        unsafeAtomicAdd(dst + 3, a3);
    }
}

// pairwise tile kernel (upper-triangle tiles only: all consumed c1<c2
// contributions have si<sj since classes are ordered in s)
__global__ void k_pairs(const float* __restrict__ sums,
                        const unsigned int* __restrict__ counts,
                        float* __restrict__ pairsum) {
    if (blockIdx.y < blockIdx.x) return;   // j0 >= i0 tiles only
    __shared__ float rI[TI][DCH + 1], rJ[TI][DCH + 1];
    __shared__ int cI[TI], cJ[TI];
    __shared__ float ps[NCLS * NCLS];
    const int b = blockIdx.z;
    const int i0 = blockIdx.x * TI, j0 = blockIdx.y * TI;
    if (threadIdx.x < NCLS * NCLS) ps[threadIdx.x] = 0.f;
    for (int t = threadIdx.x; t < TI * DCH; t += blockDim.x) {
        const int r = t >> 6, d = t & 63;
        const int si = i0 + r, sj = j0 + r;
        float vi = 0.f, vj = 0.f;
        if (si < NSEG) {
            const float c = fmaxf((float)counts[b * NSEG + si], 1.f);
            vi = sums[((size_t)b * NSEG + si) * DCH + d] / c;
        }
        if (sj < NSEG) {
            const float c = fmaxf((float)counts[b * NSEG + sj], 1.f);
            vj = sums[((size_t)b * NSEG + sj) * DCH + d] / c;
        }
        rI[r][d] = vi;
        rJ[r][d] = vj;
    }
    if (threadIdx.x < TI) {
        int si = i0 + threadIdx.x;
        bool ok = (si > 0 && si < NSEG && counts[b * NSEG + si] >= 2u);
        cI[threadIdx.x] = ok ? (si - 1) / KSTR : -1;
        int sj = j0 + threadIdx.x;
        ok = (sj > 0 && sj < NSEG && counts[b * NSEG + sj] >= 2u);
        cJ[threadIdx.x] = ok ? (sj - 1) / KSTR : -1;
    }
    __syncthreads();
    const int ti = threadIdx.x >> 4, tj = threadIdx.x & 15;
    const int ci = cI[ti], cj = cJ[tj];
    if (ci >= 0 && ci < NCLS && cj >= 0 && cj < NCLS) {
        float s = 0.f;
        #pragma unroll
        for (int d = 0; d < DCH; ++d) s += fabsf(rI[ti][d] - rJ[tj][d]);
        unsafeAtomicAdd(&ps[ci * NCLS + cj], s * (1.f / DCH));
    }
    __syncthreads();
    if (threadIdx.x < NCLS * NCLS && ps[threadIdx.x] != 0.f)
        unsafeAtomicAdd(&pairsum[b * NCLS * NCLS + threadIdx.x], ps[threadIdx.x]);
}

__global__ void k_final(const unsigned int* __restrict__ counts,
                        const float* __restrict__ pairsum,
                        float* __restrict__ out) {
    __shared__ int nc[BATCH][NCLS];
    __shared__ float psl[BATCH * NCLS * NCLS];
    const int tid = threadIdx.x;
    if (tid < BATCH * NCLS) nc[tid / NCLS][tid % NCLS] = 0;
    if (tid < BATCH * NCLS * NCLS) psl[tid] = pairsum[tid];
    __syncthreads();
    for (int t = tid; t < BATCH * NSEG; t += blockDim.x) {
        const int b = t / NSEG, s = t % NSEG;
        if (s > 0 && counts[t] >= 2u) {
            const int c = (s - 1) / KSTR;
            if (c >= 0 && c < NCLS) atomicAdd(&nc[b][c], 1);
        }
    }
    __syncthreads();
    if (tid == 0) {
        float tot_s = 0.f, tot_c = 0.f;
        for (int b = 0; b < BATCH; ++b)
            for (int c1 = 0; c1 < NCLS; ++c1)
                for (int c2 = c1 + 1; c2 < NCLS; ++c2) {
                    const float np = (float)nc[b][c1] * (float)nc[b][c2];
                    if (np > 0.f) {
                        const float r = psl[b * NCLS * NCLS + c1 * NCLS + c2] / np;
                        tot_s += (r < 1.f) ? 0.5f * r * r : r - 0.5f;
                        tot_c += 1.f;
                    }
                }
        float mh = tot_s / fmaxf(tot_c, 1.f);
        mh = fmaxf(mh, 1e-12f);
        out[0] = (tot_c > 0.f) ? -logf(mh / (float)BATCH) : 0.f;
    }
}

extern "C" void kernel_launch(void* const* d_in, const int* in_sizes, int n_in,
                              void* d_out, int out_size, void* d_ws, size_t ws_size,
                              hipStream_t stream) {
    const float* feat = (const float*)d_in[0];
    const int* lab = (const int*)d_in[1];
    const int* idx = (const int*)d_in[2];
    float* out = (float*)d_out;
    char* ws = (char*)d_ws;

    float* pairsum        = (float*)(ws + OFF_PAIR);
    float* sums           = (float*)(ws + OFF_SUM);
    unsigned int* counts  = (unsigned int*)(ws + OFF_CNT);
    unsigned int* bhist   = (unsigned int*)(ws + OFF_BHIST);
    unsigned short* keys  = (unsigned short*)(ws + OFF_KEYS);
    unsigned int* posOf   = (unsigned int*)(ws + OFF_POS);
    unsigned short* featS = (unsigned short*)(ws + OFF_FEATS);

    k_keys<<<dim3(NBLK, BATCH), 256, 0, stream>>>(lab, idx, keys, bhist, (float4*)ws);
    k_scanA<<<dim3((NSEG + 3) / 4, BATCH), 256, 0, stream>>>(bhist, counts);
    k_scatter<<<dim3(NBLK, BATCH), 256, 0, stream>>>(keys, bhist, counts, posOf);
    k_tpose<<<dim3(PIX / 64, BATCH), 256, 0, stream>>>(feat, posOf, featS);
    k_segsum<<<dim3(PIX / 256, BATCH), 256, 0, stream>>>(featS, counts, sums);
    k_pairs<<<dim3((NSEG + TI - 1) / TI, (NSEG + TI - 1) / TI, BATCH), 256, 0, stream>>>(
        sums, counts, pairsum);
    k_final<<<1, 256, 0, stream>>>(counts, pairsum, out);
}

// Round 17
// 91.973 us; speedup vs baseline: 1.3526x; 1.3526x over previous
//
#include <hip/hip_runtime.h>
#include <math.h>

#define BATCH 2
#define DCH 64
#define PIX (512 * 512)
#define NCLS 5
#define IGNORE_LB 255
#define KSTR 129                      // fixed injective key stride (> MAX_INDEX)
#define NSEG 645                      // KSTR*4 + 128 + 1
#define NBLK 64                       // key/scatter blocks per batch (4096 px each)
#define TI 16                         // pair-tile edge

// ---- workspace layout (bytes) ----
// zero region (zeroed inside k_keys each call):
#define OFF_PAIR  0                                    // float pairsum[BATCH][25]
#define OFF_SUM   256                                  // float sums[BATCH][NSEG][DCH]
#define ZERO_BYTES 330496
// non-zeroed (fully rewritten each call):
#define OFF_CNT   330496                               // uint counts[BATCH][NSEG]
#define OFF_BHIST 341248                               // uint blockHist[BATCH][NBLK][NSEG]
#define OFF_KEYS  671488                               // ushort keys[BATCH][PIX]
#define OFF_POS   2768640                              // uint posOf[BATCH][PIX]
#define OFF_FEATS 4865792                              // ushort(bf16) featS[BATCH][PIX][DCH]

__device__ __forceinline__ unsigned short f2bf(float f) {   // round-to-nearest-even
    unsigned int u = __float_as_uint(f);
    u += 0x7FFFu + ((u >> 16) & 1u);
    return (unsigned short)(u >> 16);
}

// contiguous 4096-px chunk per block; per-block histogram dumped non-atomically.
// Also cooperatively zeroes the pairsum+sums region (first reader: k_segsum).
__global__ void k_keys(const int* __restrict__ lab, const int* __restrict__ idx,
                       unsigned short* __restrict__ keys,
                       unsigned int* __restrict__ blockHist,
                       float4* __restrict__ zeroReg) {
    __shared__ unsigned int hist[NSEG];
    const int b = blockIdx.y, blk = blockIdx.x;
    {   // zero-fold: 128 blocks cover ZERO_BYTES/16 float4s
        const int n4 = ZERO_BYTES / 16;
        const int bid = b * NBLK + blk;
        const int per = (n4 + NBLK * BATCH - 1) / (NBLK * BATCH);
        const int lo = bid * per;
        const int hi = (lo + per < n4) ? lo + per : n4;
        for (int i = lo + threadIdx.x; i < hi; i += blockDim.x)
            zeroReg[i] = make_float4(0.f, 0.f, 0.f, 0.f);
    }
    for (int i = threadIdx.x; i < NSEG; i += blockDim.x) hist[i] = 0u;
    __syncthreads();
    const int4* lb = (const int4*)(lab + (size_t)b * PIX);
    const int4* ib = (const int4*)(idx + (size_t)b * PIX);
    unsigned short* kb = keys + (size_t)b * PIX;
    #pragma unroll
    for (int it = 0; it < 4; ++it) {
        const int g = blk * 1024 + it * 256 + threadIdx.x;   // int4 group
        const int4 l4 = lb[g];
        const int4 x4 = ib[g];
        int k[4];
        k[0] = (l4.x == IGNORE_LB) ? 0 : KSTR * l4.x + x4.x;
        k[1] = (l4.y == IGNORE_LB) ? 0 : KSTR * l4.y + x4.y;
        k[2] = (l4.z == IGNORE_LB) ? 0 : KSTR * l4.z + x4.z;
        k[3] = (l4.w == IGNORE_LB) ? 0 : KSTR * l4.w + x4.w;
        ushort4 o;
        o.x = (unsigned short)k[0]; o.y = (unsigned short)k[1];
        o.z = (unsigned short)k[2]; o.w = (unsigned short)k[3];
        *(ushort4*)(kb + 4 * g) = o;
        #pragma unroll
        for (int j = 0; j < 4; ++j) atomicAdd(&hist[k[j]], 1u);
    }
    __syncthreads();
    unsigned int* bh = blockHist + ((size_t)b * NBLK + blk) * NSEG;
    for (int i = threadIdx.x; i < NSEG; i += blockDim.x) bh[i] = hist[i];
}

// parallel column scan: one 64-lane wave per segment-column; lane = blk.
// Converts blockHist[*][s] to per-block exclusive prefixes; writes counts[s].
__global__ void k_scanA(unsigned int* __restrict__ blockHist,
                        unsigned int* __restrict__ counts) {
    const int b = blockIdx.y;
    const int s = blockIdx.x * 4 + (threadIdx.x >> 6);
    const int lane = threadIdx.x & 63;
    if (s >= NSEG) return;
    unsigned int* col = blockHist + (size_t)b * NBLK * NSEG + s;
    const unsigned int v0 = col[(size_t)lane * NSEG];
    unsigned int v = v0;
    #pragma unroll
    for (int o = 1; o < 64; o <<= 1) {
        unsigned int t = __shfl_up(v, o, 64);
        if (lane >= o) v += t;
    }
    col[(size_t)lane * NSEG] = v - v0;          // exclusive
    if (lane == 63) counts[b * NSEG + s] = v;   // column total
}

// positions via LDS cursor; base recomputed per-block from counts by wave 0.
__global__ void k_scatter(const unsigned short* __restrict__ keys,
                          const unsigned int* __restrict__ blockHist,
                          const unsigned int* __restrict__ counts,
                          unsigned int* __restrict__ posOf) {
    __shared__ unsigned int baseL[NSEG];
    __shared__ unsigned int cur[NSEG];
    const int b = blockIdx.y, blk = blockIdx.x;
    if (threadIdx.x < 64) {
        const int lane = threadIdx.x;
        unsigned int carry = 0u;
        for (int c = 0; c < (NSEG + 63) / 64; ++c) {
            const int s = c * 64 + lane;
            unsigned int v0 = (s < NSEG) ? counts[b * NSEG + s] : 0u;
            unsigned int v = v0;
            #pragma unroll
            for (int o = 1; o < 64; o <<= 1) {
                unsigned int t = __shfl_up(v, o, 64);
                if (lane >= o) v += t;
            }
            if (s < NSEG) baseL[s] = carry + (v - v0);
            carry += __shfl(v, 63, 64);
        }
    }
    __syncthreads();
    const unsigned int* bh = blockHist + ((size_t)b * NBLK + blk) * NSEG;
    for (int s = threadIdx.x; s < NSEG; s += blockDim.x)
        cur[s] = baseL[s] + bh[s];
    __syncthreads();
    const unsigned short* kb = keys + (size_t)b * PIX;
    unsigned int* po = posOf + (size_t)b * PIX;
    #pragma unroll
    for (int it = 0; it < 4; ++it) {
        const int g = blk * 1024 + it * 256 + threadIdx.x;
        const ushort4 k4 = *(const ushort4*)(kb + 4 * g);
        const unsigned short kk[4] = {k4.x, k4.y, k4.z, k4.w};
        #pragma unroll
        for (int j = 0; j < 4; ++j) {
            const unsigned int pos = atomicAdd(&cur[kk[j]], 1u);
            po[4 * g + j] = pos;
        }
    }
}

// transpose [D][P] -> sorted [pos][D] with f32->bf16, 64x64 tiles via LDS
__global__ __launch_bounds__(256) void k_tpose(const float* __restrict__ feat,
                                               const unsigned int* __restrict__ posOf,
                                               unsigned short* __restrict__ featS) {
    __shared__ unsigned short tile[64][72];   // 144B rows (16B-aligned), 9.2KB
    __shared__ unsigned int posLDS[64];
    const int b = blockIdx.y;
    const int P0 = blockIdx.x * 64;
    const int tid = threadIdx.x;
    if (tid < 64) posLDS[tid] = posOf[(size_t)b * PIX + P0 + tid];
    const float* fb = feat + (size_t)b * DCH * PIX;
    #pragma unroll
    for (int i = 0; i < 4; ++i) {
        const int idx = i * 256 + tid;
        const int ch = idx >> 4, px4 = idx & 15;
        const float4 v = *(const float4*)(fb + (size_t)ch * PIX + P0 + 4 * px4);
        const int col = ch ^ ((px4 & 7) << 3);
        tile[4 * px4 + 0][col] = f2bf(v.x);
        tile[4 * px4 + 1][col] = f2bf(v.y);
        tile[4 * px4 + 2][col] = f2bf(v.z);
        tile[4 * px4 + 3][col] = f2bf(v.w);
    }
    __syncthreads();
    unsigned short* fS = featS + (size_t)b * PIX * DCH;
    #pragma unroll
    for (int i = 0; i < 4; ++i) {
        const int idx = i * 256 + tid;
        const int px = idx >> 4, c4 = idx & 15;
        const int col0 = (4 * c4) ^ (((px >> 2) & 7) << 3);
        const uint2 w = *(const uint2*)&tile[px][col0];
        *(uint2*)(fS + ((size_t)posLDS[px]) * DCH + 4 * c4) = w;
    }
}

// sorted segment sums: lane = channel; per-row key derived by binary search
// over base[] (largest s with base[s] <= q — correct across empty segments
// since base[t+1] = base[t]+count[t]). Wave-uniform key via readlane,
// register accumulate, flush on key change. NOTE: the wave-uniform scalar
// key/branch is the asset — 3 widening attempts (R8/R11/R16) all regressed.
__global__ __launch_bounds__(256) void k_segsum(const unsigned short* __restrict__ featS,
                                                const unsigned int* __restrict__ counts,
                                                float* __restrict__ sums) {
    __shared__ unsigned int baseL[NSEG];
    const int b = blockIdx.y;
    if (threadIdx.x < 64) {
        const int lane = threadIdx.x;
        unsigned int carry = 0u;
        for (int c = 0; c < (NSEG + 63) / 64; ++c) {
            const int s = c * 64 + lane;
            unsigned int v0 = (s < NSEG) ? counts[b * NSEG + s] : 0u;
            unsigned int v = v0;
            #pragma unroll
            for (int o = 1; o < 64; o <<= 1) {
                unsigned int t = __shfl_up(v, o, 64);
                if (lane >= o) v += t;
            }
            if (s < NSEG) baseL[s] = carry + (v - v0);
            carry += __shfl(v, 63, 64);
        }
    }
    __syncthreads();
    const int lane = threadIdx.x & 63, wid = threadIdx.x >> 6;
    const int q0 = (blockIdx.x * 4 + wid) * 64;
    const unsigned int q = (unsigned int)(q0 + lane);
    int lo = 0, hi = NSEG - 1;
    #pragma unroll
    for (int it = 0; it < 10; ++it) {      // ceil(log2(645)) = 10
        const int mid = (lo + hi + 1) >> 1;
        if (baseL[mid] <= q) lo = mid; else hi = mid - 1;
    }
    const int sk = lo;                     // this row's segment key
    const unsigned short* fS = featS + (size_t)b * PIX * DCH;
    int cur = __shfl(sk, 0, 64);
    float acc = 0.f;
    #pragma unroll 8
    for (int j = 0; j < 64; ++j) {
        const int k = __shfl(sk, j, 64);
        const unsigned int u = fS[(size_t)(q0 + j) * DCH + lane];
        const float f = __uint_as_float(u << 16);
        if (k != cur) {
            unsafeAtomicAdd(&sums[((size_t)b * NSEG + cur) * DCH + lane], acc);
            acc = 0.f;
            cur = k;
        }
        acc += f;
    }
    unsafeAtomicAdd(&sums[((size_t)b * NSEG + cur) * DCH + lane], acc);
}

// pairwise tile kernel (upper-triangle tiles only: all consumed c1<c2
// contributions have si<sj since classes are ordered in s)
__global__ void k_pairs(const float* __restrict__ sums,
                        const unsigned int* __restrict__ counts,
                        float* __restrict__ pairsum) {
    if (blockIdx.y < blockIdx.x) return;   // j0 >= i0 tiles only
    __shared__ float rI[TI][DCH + 1], rJ[TI][DCH + 1];
    __shared__ int cI[TI], cJ[TI];
    __shared__ float ps[NCLS * NCLS];
    const int b = blockIdx.z;
    const int i0 = blockIdx.x * TI, j0 = blockIdx.y * TI;
    if (threadIdx.x < NCLS * NCLS) ps[threadIdx.x] = 0.f;
    for (int t = threadIdx.x; t < TI * DCH; t += blockDim.x) {
        const int r = t >> 6, d = t & 63;
        const int si = i0 + r, sj = j0 + r;
        float vi = 0.f, vj = 0.f;
        if (si < NSEG) {
            const float c = fmaxf((float)counts[b * NSEG + si], 1.f);
            vi = sums[((size_t)b * NSEG + si) * DCH + d] / c;
        }
        if (sj < NSEG) {
            const float c = fmaxf((float)counts[b * NSEG + sj], 1.f);
            vj = sums[((size_t)b * NSEG + sj) * DCH + d] / c;
        }
        rI[r][d] = vi;
        rJ[r][d] = vj;
    }
    if (threadIdx.x < TI) {
        int si = i0 + threadIdx.x;
        bool ok = (si > 0 && si < NSEG && counts[b * NSEG + si] >= 2u);
        cI[threadIdx.x] = ok ? (si - 1) / KSTR : -1;
        int sj = j0 + threadIdx.x;
        ok = (sj > 0 && sj < NSEG && counts[b * NSEG + sj] >= 2u);
        cJ[threadIdx.x] = ok ? (sj - 1) / KSTR : -1;
    }
    __syncthreads();
    const int ti = threadIdx.x >> 4, tj = threadIdx.x & 15;
    const int ci = cI[ti], cj = cJ[tj];
    if (ci >= 0 && ci < NCLS && cj >= 0 && cj < NCLS) {
        float s = 0.f;
        #pragma unroll
        for (int d = 0; d < DCH; ++d) s += fabsf(rI[ti][d] - rJ[tj][d]);
        unsafeAtomicAdd(&ps[ci * NCLS + cj], s * (1.f / DCH));
    }
    __syncthreads();
    if (threadIdx.x < NCLS * NCLS && ps[threadIdx.x] != 0.f)
        unsafeAtomicAdd(&pairsum[b * NCLS * NCLS + threadIdx.x], ps[threadIdx.x]);
}

__global__ void k_final(const unsigned int* __restrict__ counts,
                        const float* __restrict__ pairsum,
                        float* __restrict__ out) {
    __shared__ int nc[BATCH][NCLS];
    __shared__ float psl[BATCH * NCLS * NCLS];
    const int tid = threadIdx.x;
    if (tid < BATCH * NCLS) nc[tid / NCLS][tid % NCLS] = 0;
    if (tid < BATCH * NCLS * NCLS) psl[tid] = pairsum[tid];
    __syncthreads();
    for (int t = tid; t < BATCH * NSEG; t += blockDim.x) {
        const int b = t / NSEG, s = t % NSEG;
        if (s > 0 && counts[t] >= 2u) {
            const int c = (s - 1) / KSTR;
            if (c >= 0 && c < NCLS) atomicAdd(&nc[b][c], 1);
        }
    }
    __syncthreads();
    if (tid == 0) {
        float tot_s = 0.f, tot_c = 0.f;
        for (int b = 0; b < BATCH; ++b)
            for (int c1 = 0; c1 < NCLS; ++c1)
                for (int c2 = c1 + 1; c2 < NCLS; ++c2) {
                    const float np = (float)nc[b][c1] * (float)nc[b][c2];
                    if (np > 0.f) {
                        const float r = psl[b * NCLS * NCLS + c1 * NCLS + c2] / np;
                        tot_s += (r < 1.f) ? 0.5f * r * r : r - 0.5f;
                        tot_c += 1.f;
                    }
                }
        float mh = tot_s / fmaxf(tot_c, 1.f);
        mh = fmaxf(mh, 1e-12f);
        out[0] = (tot_c > 0.f) ? -logf(mh / (float)BATCH) : 0.f;
    }
}

extern "C" void kernel_launch(void* const* d_in, const int* in_sizes, int n_in,
                              void* d_out, int out_size, void* d_ws, size_t ws_size,
                              hipStream_t stream) {
    const float* feat = (const float*)d_in[0];
    const int* lab = (const int*)d_in[1];
    const int* idx = (const int*)d_in[2];
    float* out = (float*)d_out;
    char* ws = (char*)d_ws;

    float* pairsum        = (float*)(ws + OFF_PAIR);
    float* sums           = (float*)(ws + OFF_SUM);
    unsigned int* counts  = (unsigned int*)(ws + OFF_CNT);
    unsigned int* bhist   = (unsigned int*)(ws + OFF_BHIST);
    unsigned short* keys  = (unsigned short*)(ws + OFF_KEYS);
    unsigned int* posOf   = (unsigned int*)(ws + OFF_POS);
    unsigned short* featS = (unsigned short*)(ws + OFF_FEATS);

    k_keys<<<dim3(NBLK, BATCH), 256, 0, stream>>>(lab, idx, keys, bhist, (float4*)ws);
    k_scanA<<<dim3((NSEG + 3) / 4, BATCH), 256, 0, stream>>>(bhist, counts);
    k_scatter<<<dim3(NBLK, BATCH), 256, 0, stream>>>(keys, bhist, counts, posOf);
    k_tpose<<<dim3(PIX / 64, BATCH), 256, 0, stream>>>(feat, posOf, featS);
    k_segsum<<<dim3(PIX / 256, BATCH), 256, 0, stream>>>(featS, counts, sums);
    k_pairs<<<dim3((NSEG + TI - 1) / TI, (NSEG + TI - 1) / TI, BATCH), 256, 0, stream>>>(
        sums, counts, pairsum);
    k_final<<<1, 256, 0, stream>>>(counts, pairsum, out);
}